// Round 18
// baseline (167.462 us; speedup 1.0000x reference)
//
#include <hip/hip_runtime.h>
#include <stdint.h>

typedef float fx4 __attribute__((ext_vector_type(4)));
typedef short s8 __attribute__((ext_vector_type(8)));
typedef short s4 __attribute__((ext_vector_type(4)));
typedef unsigned int u32;
typedef u32 ux4 __attribute__((ext_vector_type(4)));

#define MTOT 16384
#define NPTS 4096

#define VMCNT5 asm volatile("s_waitcnt vmcnt(5)" ::: "memory")
#define VMCNT4 asm volatile("s_waitcnt vmcnt(4)" ::: "memory")
#define VMCNT0 asm volatile("s_waitcnt vmcnt(0)" ::: "memory")
#define LGKM0  asm volatile("s_waitcnt lgkmcnt(0)" ::: "memory")
#define SBAR   asm volatile("s_barrier" ::: "memory")
#define SCHED0 __builtin_amdgcn_sched_barrier(0)

__device__ __forceinline__ float b2f(short s) {
    return __uint_as_float(((unsigned)(unsigned short)s) << 16);
}
__device__ __forceinline__ short f2b(float f) {
    unsigned u = __float_as_uint(f);
    u += 0x7fffu + ((u >> 16) & 1u);
    return (short)(u >> 16);
}
__device__ __forceinline__ void g2l16(const void* g, void* l) {
    __builtin_amdgcn_global_load_lds(
        (const __attribute__((address_space(1))) unsigned int*)g,
        (__attribute__((address_space(3))) unsigned int*)l, 16, 0, 0);
}
__device__ __forceinline__ void g2l4(const void* g, void* l) {
    __builtin_amdgcn_global_load_lds(
        (const __attribute__((address_space(1))) unsigned int*)g,
        (__attribute__((address_space(3))) unsigned int*)l, 4, 0, 0);
}

// ---------------------------------------------------------------------------
// Weight transpose + bf16. swz=1: chunked LDS-image layout per 32-k chunk.
// ---------------------------------------------------------------------------
struct WTDesc {
    const float* W[8];
    short* Bt[8];
    int K[8];
    int N[8];
    int Kp[8];
    int swz[8];
    int base[9];
};

__global__ __launch_bounds__(256) void wtrans8_kernel(WTDesc d)
{
    int idx = blockIdx.x * 256 + threadIdx.x;
    if (idx >= d.base[8]) return;
    int s = 0;
#pragma unroll
    for (int t = 1; t < 8; ++t) if (idx >= d.base[t]) s = t;
    int local = idx - d.base[s];
    int N = d.N[s];
    if (d.swz[s]) {
        int c = local / 10240, r = local - c * 10240;
        int n = r >> 5, q = r & 31, slot = q >> 3, t = q & 7;
        int kl = ((slot ^ ((n >> 1) & 3)) << 3) | t;
        int k = c * 32 + kl;
        d.Bt[s][local] = f2b(d.W[s][(size_t)k * N + n]);
    } else {
        int Kp = d.Kp[s], K = d.K[s];
        int n = local / Kp, k = local - n * Kp;
        d.Bt[s][local] = (k < K) ? f2b(d.W[s][(size_t)k * N + n]) : (short)0;
    }
}

// ---------------------------------------------------------------------------
// Fused kNN-part + A-prepass (unchanged from R17 — passing, best).
// ---------------------------------------------------------------------------
#define SEGW 132
#define KCAP 40

template<int K>
__device__ __forceinline__ void aprep_one(
    const float* __restrict__ src, short* __restrict__ dst, int aid)
{
    constexpr int KT8 = K * 4;
    int mtile = aid / KT8;
    int r8 = aid - mtile * KT8;
    int r2 = r8 * 8;
    int chunk = r2 >> 10;
    int within = r2 & 1023;
    int r = within >> 5, q = within & 31;
    int slot = q >> 3;
    int k = chunk * 32 + ((slot ^ ((r >> 1) & 3)) << 3);
    int row = mtile * 32 + r;
    const float* sp = src + (size_t)row * K + k;
    fx4 v0 = *(const fx4*)sp, v1 = *(const fx4*)(sp + 4);
    s8 o;
    o[0] = f2b(v0[0]); o[1] = f2b(v0[1]); o[2] = f2b(v0[2]); o[3] = f2b(v0[3]);
    o[4] = f2b(v1[0]); o[5] = f2b(v1[1]); o[6] = f2b(v1[2]); o[7] = f2b(v1[3]);
    *(s8*)(dst + (size_t)aid * 8) = o;
}

__global__ __launch_bounds__(512) void knap_kernel(
    const float* __restrict__ pos, u32* __restrict__ keys,
    const float* __restrict__ f0, const float* __restrict__ f1, const float* __restrict__ f2,
    short* __restrict__ a0, short* __restrict__ a1, short* __restrict__ a2)
{
    __shared__ float xs[8 * SEGW], ys[8 * SEGW], zs[8 * SEGW];
    __shared__ u32 cand[64 * KCAP];
    __shared__ u32 samp[64 * 16];
    __shared__ u32 tauA[64];
    __shared__ int cnt[64];

    int bid = blockIdx.x;
    if (bid >= 1024) {
        int g = (bid - 1024) * 512 + threadIdx.x;
        if (g < 1572864)      aprep_one<768>(f2, a2, g);
        else if (g < 2621440) aprep_one<512>(f1, a1, g - 1572864);
        else                  aprep_one<256>(f0, a0, g - 2621440);
        return;
    }

    int b   = bid >> 8;
    int cc  = (bid >> 6) & 3;
    int pch = bid & 63;
    int tid = threadIdx.x;
    int jb  = cc << 10;

    if (tid < 64) cnt[tid] = 0;
    for (int idx = tid; idx < 1024; idx += 512) {
        int seg = idx >> 7, o = idx & 127;
        const float* pp = pos + (size_t)(b * NPTS + jb + idx) * 3;
        xs[seg * SEGW + o] = pp[0];
        ys[seg * SEGW + o] = pp[1];
        zs[seg * SEGW + o] = pp[2];
    }
    __syncthreads();

    int lp = tid >> 3, q = tid & 7;
    int gi = pch * 64 + lp;
    const float* mp = pos + (size_t)(b * NPTS + gi) * 3;
    float mx = mp[0], my = mp[1], mz = mp[2];

    const float* xsq = xs + q * SEGW;
    const float* ysq = ys + q * SEGW;
    const float* zsq = zs + q * SEGW;
    int jg0 = jb + q * 128;

    u32 h0 = 0xFFFFFFFFu, h1v = 0xFFFFFFFFu;
    for (int jj = 0; jj < 128; jj += 4) {
        fx4 xv = *reinterpret_cast<const fx4*>(xsq + jj);
        fx4 yv = *reinterpret_cast<const fx4*>(ysq + jj);
        fx4 zv = *reinterpret_cast<const fx4*>(zsq + jj);
#pragma unroll
        for (int u = 0; u < 4; ++u) {
            float dx = xv[u] - mx, dy = yv[u] - my, dz = zv[u] - mz;
            float d2 = fmaf(dx, dx, fmaf(dy, dy, dz * dz));
            u32 d2m = __float_as_uint(d2) & 0xFFFFF000u;
            if (jg0 + jj + u == gi) d2m = 0xFFFFFFFFu;
            u32 lo = (d2m < h0) ? d2m : h0;
            u32 hi = (d2m < h0) ? h0 : d2m;
            h0 = lo;
            h1v = (hi < h1v) ? hi : h1v;
        }
    }
    u32 m0 = h0 | (u32)(q * 2);
    u32 m1 = h1v | (u32)(q * 2 + 1);
    samp[lp * 16 + q * 2]     = m0;
    samp[lp * 16 + q * 2 + 1] = m1;
    __syncthreads();

    {
        ux4 sv0 = *(ux4*)&samp[lp * 16];
        ux4 sv1 = *(ux4*)&samp[lp * 16 + 4];
        ux4 sv2 = *(ux4*)&samp[lp * 16 + 8];
        ux4 sv3 = *(ux4*)&samp[lp * 16 + 12];
        int r0 = 0, r1 = 0;
#pragma unroll
        for (int i = 0; i < 4; ++i) {
            r0 += (sv0[i] < m0) + (sv1[i] < m0) + (sv2[i] < m0) + (sv3[i] < m0);
            r1 += (sv0[i] < m1) + (sv1[i] < m1) + (sv2[i] < m1) + (sv3[i] < m1);
        }
        if (r0 == 11) tauA[lp] = m0;
        if (r1 == 11) tauA[lp] = m1;
    }
    __syncthreads();
    u32 tau = tauA[lp];

    for (int jj = 0; jj < 128; jj += 4) {
        fx4 xv = *reinterpret_cast<const fx4*>(xsq + jj);
        fx4 yv = *reinterpret_cast<const fx4*>(ysq + jj);
        fx4 zv = *reinterpret_cast<const fx4*>(zsq + jj);
#pragma unroll
        for (int u = 0; u < 4; ++u) {
            float dx = xv[u] - mx, dy = yv[u] - my, dz = zv[u] - mz;
            float d2 = fmaf(dx, dx, fmaf(dy, dy, dz * dz));
            int jg = jg0 + jj + u;
            u32 d2m = __float_as_uint(d2) & 0xFFFFF000u;
            if (jg == gi) d2m = 0xFFFFFFFFu;
            if (d2m <= tau) {
                int slot = atomicAdd(&cnt[lp], 1);
                if (slot < KCAP) cand[lp * KCAP + slot] = d2m | (u32)jg;
            }
        }
    }
    __syncthreads();

    int n = cnt[lp];
    u32 out[12];
    if (n <= KCAP) {
        u32 e0, e1, e2, e3, e4;
        e0 = (q      < n) ? cand[lp * KCAP + q]      : 0xFFFFFFFFu;
        e1 = (q + 8  < n) ? cand[lp * KCAP + q + 8]  : 0xFFFFFFFFu;
        e2 = (q + 16 < n) ? cand[lp * KCAP + q + 16] : 0xFFFFFFFFu;
        e3 = (q + 24 < n) ? cand[lp * KCAP + q + 24] : 0xFFFFFFFFu;
        e4 = (q + 32 < n) ? cand[lp * KCAP + q + 32] : 0xFFFFFFFFu;
#define CE(a, b) { u32 t0 = (a < b) ? a : b; u32 t1 = (a < b) ? b : a; a = t0; b = t1; }
        CE(e0, e1) CE(e1, e2) CE(e2, e3) CE(e3, e4)
        CE(e0, e1) CE(e1, e2) CE(e2, e3)
        CE(e0, e1) CE(e1, e2)
        CE(e0, e1)
#undef CE
        cand[lp * KCAP + q]      = e0;
        cand[lp * KCAP + q + 8]  = e1;
        cand[lp * KCAP + q + 16] = e2;
        cand[lp * KCAP + q + 24] = e3;
        cand[lp * KCAP + q + 32] = e4;
        int ptr = 0;
        u32 head = e0;
#pragma unroll
        for (int r = 0; r < 12; ++r) {
            u32 m = head;
            u32 o1 = __shfl_xor(m, 4, 8); m = (o1 < m) ? o1 : m;
            u32 o2 = __shfl_xor(m, 2, 8); m = (o2 < m) ? o2 : m;
            u32 o3 = __shfl_xor(m, 1, 8); m = (o3 < m) ? o3 : m;
            if (m == head) {
                ++ptr;
                head = (ptr < 5) ? cand[lp * KCAP + q + ptr * 8] : 0xFFFFFFFFu;
            }
            out[r] = m;
        }
    } else {
        u32 hk[12];
#pragma unroll
        for (int k = 0; k < 12; ++k) hk[k] = 0xFFFFFFFFu;
        for (int jj = 0; jj < 128; jj += 4) {
            fx4 xv = *reinterpret_cast<const fx4*>(xsq + jj);
            fx4 yv = *reinterpret_cast<const fx4*>(ysq + jj);
            fx4 zv = *reinterpret_cast<const fx4*>(zsq + jj);
#pragma unroll
            for (int u = 0; u < 4; ++u) {
                float dx = xv[u] - mx, dy = yv[u] - my, dz = zv[u] - mz;
                float d2 = fmaf(dx, dx, fmaf(dy, dy, dz * dz));
                int jg = jg0 + jj + u;
                u32 key = (__float_as_uint(d2) & 0xFFFFF000u) | (u32)jg;
                if (jg == gi) key = 0xFFFFFFFFu;
                if (key < hk[11]) {
                    hk[11] = key;
#pragma unroll
                    for (int k = 11; k >= 1; --k) {
                        u32 a = hk[k], bb = hk[k - 1];
                        u32 mn = (a < bb) ? a : bb;
                        u32 mxv = (a < bb) ? bb : a;
                        hk[k - 1] = mn; hk[k] = mxv;
                    }
                }
            }
        }
#pragma unroll
        for (int r = 0; r < 12; ++r) {
            u32 m = hk[0];
            u32 o1 = __shfl_xor(m, 4, 8); m = (o1 < m) ? o1 : m;
            u32 o2 = __shfl_xor(m, 2, 8); m = (o2 < m) ? o2 : m;
            u32 o3 = __shfl_xor(m, 1, 8); m = (o3 < m) ? o3 : m;
            if (m == hk[0]) {
#pragma unroll
                for (int k = 0; k < 11; ++k) hk[k] = hk[k + 1];
                hk[11] = 0xFFFFFFFFu;
            }
            out[r] = m;
        }
    }

    size_t kb = ((size_t)(b * NPTS + gi) * 4 + cc) * 12;
    if (q == 0) *reinterpret_cast<ux4*>(&keys[kb])     = (ux4){out[0], out[1], out[2], out[3]};
    if (q == 1) *reinterpret_cast<ux4*>(&keys[kb + 4]) = (ux4){out[4], out[5], out[6], out[7]};
    if (q == 2) *reinterpret_cast<ux4*>(&keys[kb + 8]) = (ux4){out[8], out[9], out[10], out[11]};
}

// ---------------------------------------------------------------------------
// kNN part 2 (unchanged)
// ---------------------------------------------------------------------------
__global__ __launch_bounds__(256) void knn_merge_kernel(
    const u32* __restrict__ keys, const int* __restrict__ labels,
    const float* __restrict__ logits, float* __restrict__ info32)
{
    __shared__ unsigned char labs[NPTS];
    int b  = blockIdx.x >> 6;
    int pc = blockIdx.x & 63;
    int tid = threadIdx.x;
    for (int idx = tid; idx < NPTS; idx += 256)
        labs[idx] = (unsigned char)labels[b * NPTS + idx];
    __syncthreads();

    int lp = tid >> 2, q = tid & 3;
    int gi = pc * 64 + lp;
    size_t kb = ((size_t)(b * NPTS + gi) * 4 + q) * 12;
    ux4 k0 = *reinterpret_cast<const ux4*>(&keys[kb]);
    ux4 k1 = *reinterpret_cast<const ux4*>(&keys[kb + 4]);
    ux4 k2 = *reinterpret_cast<const ux4*>(&keys[kb + 8]);
    u32 hk[12];
    hk[0] = k0[0]; hk[1] = k0[1]; hk[2] = k0[2]; hk[3] = k0[3];
    hk[4] = k1[0]; hk[5] = k1[1]; hk[6] = k1[2]; hk[7] = k1[3];
    hk[8] = k2[0]; hk[9] = k2[1]; hk[10] = k2[2]; hk[11] = k2[3];

    int mylab = (int)labs[gi];
    float sum_d = 0.f, sum_d2 = 0.f, sum_diff = 0.f, same_d = 0.f, bmin = 3.0e38f;
#pragma unroll
    for (int r = 0; r < 12; ++r) {
        u32 m = hk[0];
        u32 o1 = __shfl_xor(m, 2, 4); m = (o1 < m) ? o1 : m;
        u32 o2 = __shfl_xor(m, 1, 4); m = (o2 < m) ? o2 : m;
        if (m == hk[0]) {
#pragma unroll
            for (int k = 0; k < 11; ++k) hk[k] = hk[k + 1];
            hk[11] = 0xFFFFFFFFu;
        }
        float d = sqrtf(__uint_as_float(m & 0xFFFFF000u));
        int j = (int)(m & 0xFFFu);
        float isdiff = ((int)labs[j] != mylab) ? 1.0f : 0.0f;
        sum_d += d;
        sum_d2 = fmaf(d, d, sum_d2);
        sum_diff += isdiff;
        same_d = fmaf(d, 1.0f - isdiff, same_d);
        if (isdiff > 0.f) bmin = fminf(bmin, d);
    }

    if (q == 0) {
        float nsame = 12.0f - sum_diff;
        float mean_d = sum_d * (1.0f / 12.0f);
        float var = fmaxf(0.f, (sum_d2 - 12.0f * mean_d * mean_d) * (1.0f / 11.0f));
        float md_eps = mean_d + 1e-6f;
        float curvature = sqrtf(var) / md_eps;
        float density = 1.0f / md_eps;
        float same_dist = same_d / (nsame + 1e-6f);
        float bdist = (bmin < 2.9e38f) ? bmin : same_dist;
        float bscore = sum_diff * (1.0f / 12.0f);

        const float* lg = logits + (size_t)(b * NPTS + gi) * 17;
        float v[17];
        float vmax = -3.0e38f;
#pragma unroll
        for (int c = 0; c < 17; ++c) { v[c] = lg[c] * (1.0f / 0.75f); vmax = fmaxf(vmax, v[c]); }
        float ssum = 0.f;
#pragma unroll
        for (int c = 0; c < 17; ++c) { v[c] = expf(v[c] - vmax); ssum += v[c]; }
        float inv = 1.0f / ssum;
        float conf = 0.f, ent = 0.f;
#pragma unroll
        for (int c = 0; c < 17; ++c) {
            float pprob = v[c] * inv;
            conf = fmaxf(conf, pprob);
            ent += pprob * logf(pprob + 1e-8f);
        }
        ent = -ent * (1.0f / 2.8332133f);

        float* op = info32 + (size_t)(b * NPTS + gi) * 32;
        fx4 o0 = {bscore, conf, ent, density};
        fx4 o1v = {curvature, bdist, 0.f, 0.f};
        fx4 zz = {0.f, 0.f, 0.f, 0.f};
        *reinterpret_cast<fx4*>(op + 0)  = o0;
        *reinterpret_cast<fx4*>(op + 4)  = o1v;
        *reinterpret_cast<fx4*>(op + 8)  = zz;
        *reinterpret_cast<fx4*>(op + 12) = zz;
        *reinterpret_cast<fx4*>(op + 16) = zz;
        *reinterpret_cast<fx4*>(op + 20) = zz;
        *reinterpret_cast<fx4*>(op + 24) = zz;
        *reinterpret_cast<fx4*>(op + 28) = zz;
    }
}

// ---------------------------------------------------------------------------
// Generic bf16-MFMA GEMM (boundary-encoder MLP only).
// ---------------------------------------------------------------------------
template<bool AF32, bool RELU, bool NMASK, bool ADDF, bool OUTF, bool OUTB>
__global__ __launch_bounds__(256) void gemm_k(
    const void* __restrict__ Ap, int lda,
    const short* __restrict__ Bt,
    const float* __restrict__ bias,
    float* __restrict__ Cf, int ldcf,
    short* __restrict__ Cb, int ldcb, int cboff,
    const float* __restrict__ Af, int ldaf,
    int N, int K, int ntiles)
{
    __shared__ short As[128 * 40];
    __shared__ short Bs[64 * 40];
    int bid = blockIdx.x;
    int mt = bid / ntiles, nt = bid - mt * ntiles;
    int m0 = mt * 128, n0 = nt * 64;
    int tid = threadIdx.x, l = tid & 63, wid = tid >> 6;
    int wm = wid & 1, wn = wid >> 1, lr = l & 15, lh = l >> 4;
    fx4 acc[4][2] = {};

    int nsteps = K >> 5;
    for (int kt = 0; kt < nsteps; ++kt) {
        int k0 = kt << 5;
        if constexpr (AF32) {
            const float* A = (const float*)Ap;
#pragma unroll
            for (int it = 0; it < 4; ++it) {
                int tt = tid + it * 256;
                int row = tt >> 3, seg = tt & 7;
                fx4 vv = *reinterpret_cast<const fx4*>(A + (size_t)(m0 + row) * lda + k0 + seg * 4);
                s4 w; w[0] = f2b(vv[0]); w[1] = f2b(vv[1]); w[2] = f2b(vv[2]); w[3] = f2b(vv[3]);
                *reinterpret_cast<s4*>(&As[row * 40 + seg * 4]) = w;
            }
        } else {
            const short* A = (const short*)Ap;
#pragma unroll
            for (int it = 0; it < 2; ++it) {
                int tt = tid + it * 256;
                int row = tt >> 2, seg = tt & 3;
                s8 vv = *reinterpret_cast<const s8*>(A + (size_t)(m0 + row) * lda + k0 + seg * 8);
                *reinterpret_cast<s8*>(&As[row * 40 + seg * 8]) = vv;
            }
        }
        {
            int row = tid >> 2, seg = tid & 3;
            s8 vb = {0, 0, 0, 0, 0, 0, 0, 0};
            if (!NMASK || (n0 + row) < N)
                vb = *reinterpret_cast<const s8*>(Bt + (size_t)(n0 + row) * K + k0 + seg * 8);
            *reinterpret_cast<s8*>(&Bs[row * 40 + seg * 8]) = vb;
        }
        __syncthreads();
        s8 af[4], bfr[2];
#pragma unroll
        for (int mf = 0; mf < 4; ++mf)
            af[mf] = *reinterpret_cast<s8*>(&As[(wm * 64 + mf * 16 + lr) * 40 + lh * 8]);
#pragma unroll
        for (int nf = 0; nf < 2; ++nf)
            bfr[nf] = *reinterpret_cast<s8*>(&Bs[(wn * 32 + nf * 16 + lr) * 40 + lh * 8]);
#pragma unroll
        for (int mf = 0; mf < 4; ++mf)
#pragma unroll
            for (int nf = 0; nf < 2; ++nf)
                acc[mf][nf] = __builtin_amdgcn_mfma_f32_16x16x32_bf16(af[mf], bfr[nf], acc[mf][nf], 0, 0, 0);
        __syncthreads();
    }

#pragma unroll
    for (int nf = 0; nf < 2; ++nf) {
        int col = n0 + wn * 32 + nf * 16 + lr;
        if (NMASK && col >= N) continue;
        float bv = bias[col];
#pragma unroll
        for (int mf = 0; mf < 4; ++mf) {
            int r0 = m0 + wm * 64 + mf * 16 + lh * 4;
#pragma unroll
            for (int rg = 0; rg < 4; ++rg) {
                float c = acc[mf][nf][rg] + bv;
                if (RELU) c = fmaxf(c, 0.0f);
                int row = r0 + rg;
                if constexpr (ADDF) c += Af[(size_t)row * ldaf + col];
                if constexpr (OUTF) Cf[(size_t)row * ldcf + col] = c;
                if constexpr (OUTB) Cb[(size_t)row * ldcb + cboff + col] = f2b(c);
            }
        }
    }
}

// ---------------------------------------------------------------------------
// MEGA v11: BM=32, 512 threads (8 waves = 2 row-groups x 4 col-groups),
// per-thread acc[5]. Same 76.3KB LDS -> 2 blocks/CU -> 16 waves/CU (2x R17).
// fp streamed to thread-private global (20 shorts/thread/scale). Live ~75
// VGPR < 128 cap. Staging: B = 4 VMEM ops, A = 1 -> VMCNT5 proj / VMCNT4 g2.
// ---------------------------------------------------------------------------
__global__ __launch_bounds__(512, 2) void mega_kernel(
    const short* __restrict__ at0, const short* __restrict__ at1, const short* __restrict__ at2,
    const short* __restrict__ btp0, const short* __restrict__ btp1, const short* __restrict__ btp2,
    const float* __restrict__ bp0, const float* __restrict__ bp1, const float* __restrict__ bp2,
    const short* __restrict__ bta1, const float* __restrict__ ba1,
    const float* __restrict__ Wa2, const float* __restrict__ ba2,
    const short* __restrict__ bto1, const float* __restrict__ bo1,
    const short* __restrict__ bto2, const float* __restrict__ bo2,
    const short* __restrict__ encb, short* __restrict__ fpb,
    float* __restrict__ outf, float* __restrict__ attn_out)
{
    __shared__ alignas(16) short smem[38144];   // 76,288 B
    char* smb = (char*)smem;
    constexpr int BB0 = 0, BB1 = 20480, AB0 = 40960, AB1 = 43008, R2B = 45056, SWF = 75776;
    constexpr size_t FPS = (size_t)512 * 512 * 20;   // shorts per scale
    float* smf = (float*)(smb + SWF);

    int tid = threadIdx.x, wid = tid >> 6, l = tid & 63;
    int wm = wid >> 2, wn = wid & 3, lr = l & 15, lh = l >> 4;
    int m0 = blockIdx.x * 32;
    short* fpt = fpb + (size_t)(blockIdx.x * 512 + tid) * 20;

    auto stageB = [&](int bbase, const short* btg, int kt) {
        const char* s = (const char*)(btg + (size_t)kt * 10240);
        int o1 = tid * 16;               // 8 KB
        int o2 = 8192 + tid * 16;        // 8 KB
        int o3 = 16384 + tid * 4;        // 2 KB
        int o4 = 18432 + tid * 4;        // 2 KB
        g2l16(s + o1, smb + bbase + o1);
        g2l16(s + o2, smb + bbase + o2);
        g2l4(s + o3, smb + bbase + o3);
        g2l4(s + o4, smb + bbase + o4);
    };
    auto stageA = [&](int abase, const short* atgm, int kt) {
        const char* s = (const char*)(atgm + (size_t)kt * 1024);
        g2l4(s + tid * 4, smb + abase + tid * 4);
    };
    auto readB = [&](int bbase, s8* bf) {
#pragma unroll
        for (int nf = 0; nf < 5; ++nf) {
            int row = wn * 80 + nf * 16 + lr;
            bf[nf] = *(const s8*)(smb + bbase + row * 64 + ((lh ^ ((row >> 1) & 3)) << 4));
        }
    };

    fx4 gacc[5] = {};

    auto do_proj = [&](const short* atgm, const short* btg, int ns,
                       const float* bias, short* fpo) {
        fx4 acc[5] = {};
        stageB(BB0, btg, 0); stageA(AB0, atgm, 0);
        stageB(BB1, btg, 1); stageA(AB1, atgm, 1);
        LGKM0;
#pragma unroll 1
        for (int kt = 0; kt < ns; ++kt) {
            if (kt < ns - 1) { VMCNT5; } else { VMCNT0; }
            SBAR;
            int cb = (kt & 1) ? BB1 : BB0;
            int ca = (kt & 1) ? AB1 : AB0;
            s8 af, bf[5];
            {
                int row = wm * 16 + lr;
                af = *(const s8*)(smb + ca + row * 64 + ((lh ^ ((row >> 1) & 3)) << 4));
            }
            readB(cb, bf);
            LGKM0; SCHED0;
            SBAR;
            if (kt + 2 < ns) { stageB(cb, btg, kt + 2); stageA(ca, atgm, kt + 2); }
#pragma unroll
            for (int nf = 0; nf < 5; ++nf)
                acc[nf] = __builtin_amdgcn_mfma_f32_16x16x32_bf16(af, bf[nf], acc[nf], 0, 0, 0);
        }
        // epilogue: fp -> thread-private global (own elements); gacc accum
#pragma unroll
        for (int nf = 0; nf < 5; ++nf) {
            float bv = bias[wn * 80 + nf * 16 + lr];
            s4 pk;
#pragma unroll
            for (int rg = 0; rg < 4; ++rg) {
                float c = acc[nf][rg] + bv;
                gacc[nf][rg] += c;
                pk[rg] = f2b(c);
            }
            *(s4*)(fpo + nf * 4) = pk;
        }
    };

    do_proj(at2 + (size_t)blockIdx.x * 24576, btp2, 24, bp2, fpt + 2 * FPS);
    do_proj(at1 + (size_t)blockIdx.x * 16384, btp1, 16, bp1, fpt + 1 * FPS);
    do_proj(at0 + (size_t)blockIdx.x * 8192,  btp0, 8,  bp0, fpt);

    // global mean -> R2 cols 0..319; enc -> cols 320..479 (swizzled writes)
#pragma unroll
    for (int nf = 0; nf < 5; ++nf) {
        int col = wn * 80 + nf * 16 + lr;
#pragma unroll
        for (int rg = 0; rg < 4; ++rg) {
            int row = wm * 16 + lh * 4 + rg;
            int bir = (col * 2) ^ (((row >> 1) & 3) << 4);
            *(short*)(smb + R2B + row * 960 + bir) = f2b(gacc[nf][rg] * (1.0f / 3.0f));
        }
    }
#pragma unroll
    for (int r = 0; r < 2; ++r) {
        int idx = tid + r * 512;
        if (idx < 640) {
            int row = idx / 20, sg = idx - row * 20;
            s8 v = *reinterpret_cast<const s8*>(encb + (size_t)(m0 + row) * 160 + sg * 8);
            int bir = (640 + sg * 16) ^ (((row >> 1) & 3) << 4);
            *(s8*)(smb + R2B + row * 960 + bir) = v;
        }
    }

    auto do_gemm2 = [&](const short* btg, int ns, fx4 (&acc)[5]) {
        stageB(BB0, btg, 0);
        stageB(BB1, btg, 1);
        LGKM0;
#pragma unroll 1
        for (int kt = 0; kt < ns; ++kt) {
            if (kt < ns - 1) { VMCNT4; } else { VMCNT0; }
            SBAR;
            int cb = (kt & 1) ? BB1 : BB0;
            s8 af, bf[5];
            {
                int row = wm * 16 + lr;
                int bir = (kt * 64 + (lh << 4)) ^ (((row >> 1) & 3) << 4);
                af = *(const s8*)(smb + R2B + row * 960 + bir);
            }
            readB(cb, bf);
            LGKM0; SCHED0;
            SBAR;
            if (kt + 2 < ns) stageB(cb, btg, kt + 2);
#pragma unroll
            for (int nf = 0; nf < 5; ++nf)
                acc[nf] = __builtin_amdgcn_mfma_f32_16x16x32_bf16(af, bf[nf], acc[nf], 0, 0, 0);
        }
    };

    // ---- a1 = relu([global|enc] @ Wa1 + ba1), K=480
    {
        fx4 acc1[5] = {};
        do_gemm2(bta1, 15, acc1);
#pragma unroll
        for (int nf = 0; nf < 5; ++nf) {
            int col = wn * 80 + nf * 16 + lr;
            float bv = ba1[col];
#pragma unroll
            for (int rg = 0; rg < 4; ++rg) {
                int row = wm * 16 + lh * 4 + rg;
                int bir = (col * 2) ^ (((row >> 1) & 3) << 4);
                *(short*)(smb + R2B + row * 960 + bir) = f2b(fmaxf(acc1[nf][rg] + bv, 0.0f));
            }
        }
    }

    // ---- a2 via VALU: threads 0..255 (8 lanes x 32 rows); Wa2 f32 in BB0
    {
        float* ws2 = (float*)smb;
        if (tid < 240)
            reinterpret_cast<fx4*>(ws2)[tid] = reinterpret_cast<const fx4*>(Wa2)[tid];
        __syncthreads();
        if (tid < 256) {
            int row = tid >> 3, g = tid & 7;
            float l0 = 0.f, l1 = 0.f, l2 = 0.f;
#pragma unroll
            for (int j = 0; j < 5; ++j) {
                int bir = (g * 80 + j * 16) ^ (((row >> 1) & 3) << 4);
                s8 v = *(const s8*)(smb + R2B + row * 960 + bir);
#pragma unroll
                for (int u = 0; u < 8; ++u) {
                    float f = b2f(v[u]);
                    const float* wp = ws2 + (g * 40 + j * 8 + u) * 3;
                    l0 = fmaf(f, wp[0], l0);
                    l1 = fmaf(f, wp[1], l1);
                    l2 = fmaf(f, wp[2], l2);
                }
            }
#pragma unroll
            for (int s = 4; s >= 1; s >>= 1) {
                l0 += __shfl_xor(l0, s, 8);
                l1 += __shfl_xor(l1, s, 8);
                l2 += __shfl_xor(l2, s, 8);
            }
            if (g == 0) {
                l0 += ba2[0]; l1 += ba2[1]; l2 += ba2[2];
                float mx = fmaxf(l0, fmaxf(l1, l2));
                float e0 = expf(l0 - mx), e1 = expf(l1 - mx), e2 = expf(l2 - mx);
                float inv = 1.0f / (e0 + e1 + e2);
                float w0 = e0 * inv, w1 = e1 * inv, w2 = e2 * inv;
                attn_out[(size_t)(m0 + row) * 3 + 0] = w0;
                attn_out[(size_t)(m0 + row) * 3 + 1] = w1;
                attn_out[(size_t)(m0 + row) * 3 + 2] = w2;
                smf[row * 4 + 0] = w0; smf[row * 4 + 1] = w1; smf[row * 4 + 2] = w2;
            }
        }
        __syncthreads();
    }

    // ---- fused = sum_s w_s * fp_s (read back own global fp) -> R2
#pragma unroll
    for (int nf = 0; nf < 5; ++nf) {
        s4 p0 = *(const s4*)(fpt + nf * 4);
        s4 p1 = *(const s4*)(fpt + 1 * FPS + nf * 4);
        s4 p2 = *(const s4*)(fpt + 2 * FPS + nf * 4);
        int col = wn * 80 + nf * 16 + lr;
#pragma unroll
        for (int rg = 0; rg < 4; ++rg) {
            int row = wm * 16 + lh * 4 + rg;
            float fv = smf[row * 4 + 0] * b2f(p0[rg])
                     + smf[row * 4 + 1] * b2f(p1[rg])
                     + smf[row * 4 + 2] * b2f(p2[rg]);
            int bir = (col * 2) ^ (((row >> 1) & 3) << 4);
            *(short*)(smb + R2B + row * 960 + bir) = f2b(fv);
        }
    }

    // ---- h = relu(fused @ Wo1 + bo1)
    {
        fx4 acch[5] = {};
        do_gemm2(bto1, 10, acch);
#pragma unroll
        for (int nf = 0; nf < 5; ++nf) {
            int col = wn * 80 + nf * 16 + lr;
            float bv = bo1[col];
#pragma unroll
            for (int rg = 0; rg < 4; ++rg) {
                int row = wm * 16 + lh * 4 + rg;
                int bir = (col * 2) ^ (((row >> 1) & 3) << 4);
                *(short*)(smb + R2B + row * 960 + bir) = f2b(fmaxf(acch[nf][rg] + bv, 0.0f));
            }
        }
    }

    // ---- out = h @ Wo2 + bo2 + gacc/3 (residual in regs)
    {
        fx4 acco[5] = {};
        do_gemm2(bto2, 10, acco);
#pragma unroll
        for (int nf = 0; nf < 5; ++nf) {
            int col = wn * 80 + nf * 16 + lr;
            float bv = bo2[col];
#pragma unroll
            for (int rg = 0; rg < 4; ++rg) {
                int row = m0 + wm * 16 + lh * 4 + rg;
                float c = acco[nf][rg] + bv + gacc[nf][rg] * (1.0f / 3.0f);
                outf[(size_t)row * 320 + col] = c;
            }
        }
    }
}

// ---------------------------------------------------------------------------
extern "C" void kernel_launch(void* const* d_in, const int* in_sizes, int n_in,
                              void* d_out, int out_size, void* d_ws, size_t ws_size,
                              hipStream_t stream)
{
    const float* feat0  = (const float*)d_in[0];
    const float* feat1  = (const float*)d_in[1];
    const float* feat2  = (const float*)d_in[2];
    const float* logits = (const float*)d_in[3];
    const int*   labels = (const int*)d_in[4];
    const float* pos    = (const float*)d_in[5];
    const float* Wp0 = (const float*)d_in[6];   const float* bp0 = (const float*)d_in[7];
    const float* Wp1 = (const float*)d_in[8];   const float* bp1 = (const float*)d_in[9];
    const float* Wp2 = (const float*)d_in[10];  const float* bp2 = (const float*)d_in[11];
    const float* Wbe1 = (const float*)d_in[12]; const float* bbe1 = (const float*)d_in[13];
    const float* Wbe2 = (const float*)d_in[14]; const float* bbe2 = (const float*)d_in[15];
    const float* Wa1 = (const float*)d_in[16];  const float* ba1 = (const float*)d_in[17];
    const float* Wa2 = (const float*)d_in[18];  const float* ba2 = (const float*)d_in[19];
    const float* Wo1 = (const float*)d_in[20];  const float* bo1 = (const float*)d_in[21];
    const float* Wo2 = (const float*)d_in[22];  const float* bo2 = (const float*)d_in[23];

    char* p = (char*)d_ws;
    auto alloc = [&](size_t bytes) { char* r = p; p += (bytes + 255) & ~(size_t)255; return r; };
    short* bt_p0  = (short*)alloc((size_t)320 * 256 * 2);
    short* bt_p1  = (short*)alloc((size_t)320 * 512 * 2);
    short* bt_p2  = (short*)alloc((size_t)320 * 768 * 2);
    short* bt_be1 = (short*)alloc((size_t)96 * 32 * 2);
    short* bt_be2 = (short*)alloc((size_t)160 * 96 * 2);
    short* bt_a1  = (short*)alloc((size_t)320 * 480 * 2);
    short* bt_o1  = (short*)alloc((size_t)320 * 320 * 2);
    short* bt_o2  = (short*)alloc((size_t)320 * 320 * 2);
    float* info32 = (float*)alloc((size_t)MTOT * 32 * 4);
    short* h1     = (short*)alloc((size_t)MTOT * 96 * 2);
    short* encb   = (short*)alloc((size_t)MTOT * 160 * 2);
    u32*   knnkeys= (u32*)alloc((size_t)MTOT * 4 * 12 * 4);
    short* abt0   = (short*)alloc((size_t)MTOT * 256 * 2);
    short* abt1   = (short*)alloc((size_t)MTOT * 512 * 2);
    short* abt2   = (short*)alloc((size_t)MTOT * 768 * 2);
    short* fpb    = (short*)alloc((size_t)3 * 512 * 512 * 20 * 2);   // 31.5 MB

    float* outf = (float*)d_out;
    float* attn_out = outf + (size_t)MTOT * 320;

    WTDesc wd;
    const float* Ws[8] = {Wp0, Wp1, Wp2, Wbe1, Wbe2, Wa1, Wo1, Wo2};
    short* Bts[8] = {bt_p0, bt_p1, bt_p2, bt_be1, bt_be2, bt_a1, bt_o1, bt_o2};
    int Ks[8]  = {256, 512, 768, 6, 96, 480, 320, 320};
    int Ns[8]  = {320, 320, 320, 96, 160, 320, 320, 320};
    int Kps[8] = {256, 512, 768, 32, 96, 480, 320, 320};
    int Sz[8]  = {1, 1, 1, 0, 0, 1, 1, 1};
    int acc = 0;
    for (int s = 0; s < 8; ++s) {
        wd.W[s] = Ws[s]; wd.Bt[s] = Bts[s];
        wd.K[s] = Ks[s]; wd.N[s] = Ns[s]; wd.Kp[s] = Kps[s]; wd.swz[s] = Sz[s];
        wd.base[s] = acc;
        acc += Ns[s] * Kps[s];
    }
    wd.base[8] = acc;
    wtrans8_kernel<<<(acc + 255) / 256, 256, 0, stream>>>(wd);

    // segregated: blocks 0..1023 knn (fill CUs with VALU work first),
    // 1024..7167 aprep (BW-bound backfill; template-const indexing)
    knap_kernel<<<7168, 512, 0, stream>>>(pos, knnkeys,
                                          feat0, feat1, feat2,
                                          abt0, abt1, abt2);
    knn_merge_kernel<<<256, 256, 0, stream>>>(knnkeys, labels, logits, info32);

    // info -> h1 (relu), N=96, K=32
    gemm_k<true, true, true, false, false, true><<<256, 256, 0, stream>>>(
        info32, 32, bt_be1, bbe1, nullptr, 0, h1, 96, 0, nullptr, 0, 96, 32, 2);
    // h1 -> enc (relu), N=160, K=96
    gemm_k<false, true, true, false, false, true><<<384, 256, 0, stream>>>(
        h1, 96, bt_be2, bbe2, nullptr, 0, encb, 160, 0, nullptr, 0, 160, 96, 3);

    mega_kernel<<<512, 512, 0, stream>>>(
        abt0, abt1, abt2,
        bt_p0, bt_p1, bt_p2,
        bp0, bp1, bp2,
        bt_a1, ba1, Wa2, ba2,
        bt_o1, bo1, bt_o2, bo2,
        encb, fpb, outf, attn_out);
}

// Round 19
// 131.667 us; speedup vs baseline: 1.2719x; 1.2719x over previous
//
#include <hip/hip_runtime.h>
#include <stdint.h>

typedef float fx4 __attribute__((ext_vector_type(4)));
typedef short s8 __attribute__((ext_vector_type(8)));
typedef short s4 __attribute__((ext_vector_type(4)));
typedef unsigned int u32;
typedef u32 ux4 __attribute__((ext_vector_type(4)));

#define MTOT 16384
#define NPTS 4096

#define VMCNT7 asm volatile("s_waitcnt vmcnt(7)" ::: "memory")
#define VMCNT5 asm volatile("s_waitcnt vmcnt(5)" ::: "memory")
#define VMCNT0 asm volatile("s_waitcnt vmcnt(0)" ::: "memory")
#define LGKM0  asm volatile("s_waitcnt lgkmcnt(0)" ::: "memory")
#define SBAR   asm volatile("s_barrier" ::: "memory")
#define SCHED0 __builtin_amdgcn_sched_barrier(0)

__device__ __forceinline__ float b2f(short s) {
    return __uint_as_float(((unsigned)(unsigned short)s) << 16);
}
__device__ __forceinline__ short f2b(float f) {
    unsigned u = __float_as_uint(f);
    u += 0x7fffu + ((u >> 16) & 1u);
    return (short)(u >> 16);
}
__device__ __forceinline__ void g2l16(const void* g, void* l) {
    __builtin_amdgcn_global_load_lds(
        (const __attribute__((address_space(1))) unsigned int*)g,
        (__attribute__((address_space(3))) unsigned int*)l, 16, 0, 0);
}
__device__ __forceinline__ void g2l4(const void* g, void* l) {
    __builtin_amdgcn_global_load_lds(
        (const __attribute__((address_space(1))) unsigned int*)g,
        (__attribute__((address_space(3))) unsigned int*)l, 4, 0, 0);
}

// ---------------------------------------------------------------------------
// Weight transpose + bf16. swz=1: chunked LDS-image layout per 32-k chunk.
// ---------------------------------------------------------------------------
struct WTDesc {
    const float* W[8];
    short* Bt[8];
    int K[8];
    int N[8];
    int Kp[8];
    int swz[8];
    int base[9];
};

__global__ __launch_bounds__(256) void wtrans8_kernel(WTDesc d)
{
    int idx = blockIdx.x * 256 + threadIdx.x;
    if (idx >= d.base[8]) return;
    int s = 0;
#pragma unroll
    for (int t = 1; t < 8; ++t) if (idx >= d.base[t]) s = t;
    int local = idx - d.base[s];
    int N = d.N[s];
    if (d.swz[s]) {
        int c = local / 10240, r = local - c * 10240;
        int n = r >> 5, q = r & 31, slot = q >> 3, t = q & 7;
        int kl = ((slot ^ ((n >> 1) & 3)) << 3) | t;
        int k = c * 32 + kl;
        d.Bt[s][local] = f2b(d.W[s][(size_t)k * N + n]);
    } else {
        int Kp = d.Kp[s], K = d.K[s];
        int n = local / Kp, k = local - n * Kp;
        d.Bt[s][local] = (k < K) ? f2b(d.W[s][(size_t)k * N + n]) : (short)0;
    }
}

// ---------------------------------------------------------------------------
// Fused kNN-part + A-prepass. Block roles SEGREGATED (knn first fills all
// CUs with VALU work, aprep backfills): bid<1024 -> knn, else aprep.
// aprep: template-constant indexing; knn: d2m-only pass A + tie-id rank.
// ---------------------------------------------------------------------------
#define SEGW 132
#define KCAP 40

template<int K>
__device__ __forceinline__ void aprep_one(
    const float* __restrict__ src, short* __restrict__ dst, int aid)
{
    constexpr int KT8 = K * 4;
    int mtile = aid / KT8;
    int r8 = aid - mtile * KT8;
    int r2 = r8 * 8;
    int chunk = r2 >> 10;
    int within = r2 & 1023;
    int r = within >> 5, q = within & 31;
    int slot = q >> 3;
    int k = chunk * 32 + ((slot ^ ((r >> 1) & 3)) << 3);
    int row = mtile * 32 + r;
    const float* sp = src + (size_t)row * K + k;
    fx4 v0 = *(const fx4*)sp, v1 = *(const fx4*)(sp + 4);
    s8 o;
    o[0] = f2b(v0[0]); o[1] = f2b(v0[1]); o[2] = f2b(v0[2]); o[3] = f2b(v0[3]);
    o[4] = f2b(v1[0]); o[5] = f2b(v1[1]); o[6] = f2b(v1[2]); o[7] = f2b(v1[3]);
    *(s8*)(dst + (size_t)aid * 8) = o;
}

__global__ __launch_bounds__(512) void knap_kernel(
    const float* __restrict__ pos, u32* __restrict__ keys,
    const float* __restrict__ f0, const float* __restrict__ f1, const float* __restrict__ f2,
    short* __restrict__ a0, short* __restrict__ a1, short* __restrict__ a2)
{
    __shared__ float xs[8 * SEGW], ys[8 * SEGW], zs[8 * SEGW];
    __shared__ u32 cand[64 * KCAP];
    __shared__ u32 samp[64 * 16];
    __shared__ u32 tauA[64];
    __shared__ int cnt[64];

    int bid = blockIdx.x;
    if (bid >= 1024) {
        int g = (bid - 1024) * 512 + threadIdx.x;
        if (g < 1572864)      aprep_one<768>(f2, a2, g);
        else if (g < 2621440) aprep_one<512>(f1, a1, g - 1572864);
        else                  aprep_one<256>(f0, a0, g - 2621440);
        return;
    }

    int b   = bid >> 8;
    int cc  = (bid >> 6) & 3;
    int pch = bid & 63;
    int tid = threadIdx.x;
    int jb  = cc << 10;

    if (tid < 64) cnt[tid] = 0;
    for (int idx = tid; idx < 1024; idx += 512) {
        int seg = idx >> 7, o = idx & 127;
        const float* pp = pos + (size_t)(b * NPTS + jb + idx) * 3;
        xs[seg * SEGW + o] = pp[0];
        ys[seg * SEGW + o] = pp[1];
        zs[seg * SEGW + o] = pp[2];
    }
    __syncthreads();

    int lp = tid >> 3, q = tid & 7;
    int gi = pch * 64 + lp;
    const float* mp = pos + (size_t)(b * NPTS + gi) * 3;
    float mx = mp[0], my = mp[1], mz = mp[2];

    const float* xsq = xs + q * SEGW;
    const float* ysq = ys + q * SEGW;
    const float* zsq = zs + q * SEGW;
    int jg0 = jb + q * 128;

    u32 h0 = 0xFFFFFFFFu, h1v = 0xFFFFFFFFu;
    for (int jj = 0; jj < 128; jj += 4) {
        fx4 xv = *reinterpret_cast<const fx4*>(xsq + jj);
        fx4 yv = *reinterpret_cast<const fx4*>(ysq + jj);
        fx4 zv = *reinterpret_cast<const fx4*>(zsq + jj);
#pragma unroll
        for (int u = 0; u < 4; ++u) {
            float dx = xv[u] - mx, dy = yv[u] - my, dz = zv[u] - mz;
            float d2 = fmaf(dx, dx, fmaf(dy, dy, dz * dz));
            u32 d2m = __float_as_uint(d2) & 0xFFFFF000u;
            if (jg0 + jj + u == gi) d2m = 0xFFFFFFFFu;
            u32 lo = (d2m < h0) ? d2m : h0;
            u32 hi = (d2m < h0) ? h0 : d2m;
            h0 = lo;
            h1v = (hi < h1v) ? hi : h1v;
        }
    }
    u32 m0 = h0 | (u32)(q * 2);
    u32 m1 = h1v | (u32)(q * 2 + 1);
    samp[lp * 16 + q * 2]     = m0;
    samp[lp * 16 + q * 2 + 1] = m1;
    __syncthreads();

    {
        ux4 sv0 = *(ux4*)&samp[lp * 16];
        ux4 sv1 = *(ux4*)&samp[lp * 16 + 4];
        ux4 sv2 = *(ux4*)&samp[lp * 16 + 8];
        ux4 sv3 = *(ux4*)&samp[lp * 16 + 12];
        int r0 = 0, r1 = 0;
#pragma unroll
        for (int i = 0; i < 4; ++i) {
            r0 += (sv0[i] < m0) + (sv1[i] < m0) + (sv2[i] < m0) + (sv3[i] < m0);
            r1 += (sv0[i] < m1) + (sv1[i] < m1) + (sv2[i] < m1) + (sv3[i] < m1);
        }
        if (r0 == 11) tauA[lp] = m0;
        if (r1 == 11) tauA[lp] = m1;
    }
    __syncthreads();
    u32 tau = tauA[lp];

    for (int jj = 0; jj < 128; jj += 4) {
        fx4 xv = *reinterpret_cast<const fx4*>(xsq + jj);
        fx4 yv = *reinterpret_cast<const fx4*>(ysq + jj);
        fx4 zv = *reinterpret_cast<const fx4*>(zsq + jj);
#pragma unroll
        for (int u = 0; u < 4; ++u) {
            float dx = xv[u] - mx, dy = yv[u] - my, dz = zv[u] - mz;
            float d2 = fmaf(dx, dx, fmaf(dy, dy, dz * dz));
            int jg = jg0 + jj + u;
            u32 d2m = __float_as_uint(d2) & 0xFFFFF000u;
            if (jg == gi) d2m = 0xFFFFFFFFu;
            if (d2m <= tau) {
                int slot = atomicAdd(&cnt[lp], 1);
                if (slot < KCAP) cand[lp * KCAP + slot] = d2m | (u32)jg;
            }
        }
    }
    __syncthreads();

    int n = cnt[lp];
    u32 out[12];
    if (n <= KCAP) {
        u32 e0, e1, e2, e3, e4;
        e0 = (q      < n) ? cand[lp * KCAP + q]      : 0xFFFFFFFFu;
        e1 = (q + 8  < n) ? cand[lp * KCAP + q + 8]  : 0xFFFFFFFFu;
        e2 = (q + 16 < n) ? cand[lp * KCAP + q + 16] : 0xFFFFFFFFu;
        e3 = (q + 24 < n) ? cand[lp * KCAP + q + 24] : 0xFFFFFFFFu;
        e4 = (q + 32 < n) ? cand[lp * KCAP + q + 32] : 0xFFFFFFFFu;
#define CE(a, b) { u32 t0 = (a < b) ? a : b; u32 t1 = (a < b) ? b : a; a = t0; b = t1; }
        CE(e0, e1) CE(e1, e2) CE(e2, e3) CE(e3, e4)
        CE(e0, e1) CE(e1, e2) CE(e2, e3)
        CE(e0, e1) CE(e1, e2)
        CE(e0, e1)
#undef CE
        cand[lp * KCAP + q]      = e0;
        cand[lp * KCAP + q + 8]  = e1;
        cand[lp * KCAP + q + 16] = e2;
        cand[lp * KCAP + q + 24] = e3;
        cand[lp * KCAP + q + 32] = e4;
        int ptr = 0;
        u32 head = e0;
#pragma unroll
        for (int r = 0; r < 12; ++r) {
            u32 m = head;
            u32 o1 = __shfl_xor(m, 4, 8); m = (o1 < m) ? o1 : m;
            u32 o2 = __shfl_xor(m, 2, 8); m = (o2 < m) ? o2 : m;
            u32 o3 = __shfl_xor(m, 1, 8); m = (o3 < m) ? o3 : m;
            if (m == head) {
                ++ptr;
                head = (ptr < 5) ? cand[lp * KCAP + q + ptr * 8] : 0xFFFFFFFFu;
            }
            out[r] = m;
        }
    } else {
        u32 hk[12];
#pragma unroll
        for (int k = 0; k < 12; ++k) hk[k] = 0xFFFFFFFFu;
        for (int jj = 0; jj < 128; jj += 4) {
            fx4 xv = *reinterpret_cast<const fx4*>(xsq + jj);
            fx4 yv = *reinterpret_cast<const fx4*>(ysq + jj);
            fx4 zv = *reinterpret_cast<const fx4*>(zsq + jj);
#pragma unroll
            for (int u = 0; u < 4; ++u) {
                float dx = xv[u] - mx, dy = yv[u] - my, dz = zv[u] - mz;
                float d2 = fmaf(dx, dx, fmaf(dy, dy, dz * dz));
                int jg = jg0 + jj + u;
                u32 key = (__float_as_uint(d2) & 0xFFFFF000u) | (u32)jg;
                if (jg == gi) key = 0xFFFFFFFFu;
                if (key < hk[11]) {
                    hk[11] = key;
#pragma unroll
                    for (int k = 11; k >= 1; --k) {
                        u32 a = hk[k], bb = hk[k - 1];
                        u32 mn = (a < bb) ? a : bb;
                        u32 mxv = (a < bb) ? bb : a;
                        hk[k - 1] = mn; hk[k] = mxv;
                    }
                }
            }
        }
#pragma unroll
        for (int r = 0; r < 12; ++r) {
            u32 m = hk[0];
            u32 o1 = __shfl_xor(m, 4, 8); m = (o1 < m) ? o1 : m;
            u32 o2 = __shfl_xor(m, 2, 8); m = (o2 < m) ? o2 : m;
            u32 o3 = __shfl_xor(m, 1, 8); m = (o3 < m) ? o3 : m;
            if (m == hk[0]) {
#pragma unroll
                for (int k = 0; k < 11; ++k) hk[k] = hk[k + 1];
                hk[11] = 0xFFFFFFFFu;
            }
            out[r] = m;
        }
    }

    size_t kb = ((size_t)(b * NPTS + gi) * 4 + cc) * 12;
    if (q == 0) *reinterpret_cast<ux4*>(&keys[kb])     = (ux4){out[0], out[1], out[2], out[3]};
    if (q == 1) *reinterpret_cast<ux4*>(&keys[kb + 4]) = (ux4){out[4], out[5], out[6], out[7]};
    if (q == 2) *reinterpret_cast<ux4*>(&keys[kb + 8]) = (ux4){out[8], out[9], out[10], out[11]};
}

// ---------------------------------------------------------------------------
// kNN part 2 (unchanged)
// ---------------------------------------------------------------------------
__global__ __launch_bounds__(256) void knn_merge_kernel(
    const u32* __restrict__ keys, const int* __restrict__ labels,
    const float* __restrict__ logits, float* __restrict__ info32)
{
    __shared__ unsigned char labs[NPTS];
    int b  = blockIdx.x >> 6;
    int pc = blockIdx.x & 63;
    int tid = threadIdx.x;
    for (int idx = tid; idx < NPTS; idx += 256)
        labs[idx] = (unsigned char)labels[b * NPTS + idx];
    __syncthreads();

    int lp = tid >> 2, q = tid & 3;
    int gi = pc * 64 + lp;
    size_t kb = ((size_t)(b * NPTS + gi) * 4 + q) * 12;
    ux4 k0 = *reinterpret_cast<const ux4*>(&keys[kb]);
    ux4 k1 = *reinterpret_cast<const ux4*>(&keys[kb + 4]);
    ux4 k2 = *reinterpret_cast<const ux4*>(&keys[kb + 8]);
    u32 hk[12];
    hk[0] = k0[0]; hk[1] = k0[1]; hk[2] = k0[2]; hk[3] = k0[3];
    hk[4] = k1[0]; hk[5] = k1[1]; hk[6] = k1[2]; hk[7] = k1[3];
    hk[8] = k2[0]; hk[9] = k2[1]; hk[10] = k2[2]; hk[11] = k2[3];

    int mylab = (int)labs[gi];
    float sum_d = 0.f, sum_d2 = 0.f, sum_diff = 0.f, same_d = 0.f, bmin = 3.0e38f;
#pragma unroll
    for (int r = 0; r < 12; ++r) {
        u32 m = hk[0];
        u32 o1 = __shfl_xor(m, 2, 4); m = (o1 < m) ? o1 : m;
        u32 o2 = __shfl_xor(m, 1, 4); m = (o2 < m) ? o2 : m;
        if (m == hk[0]) {
#pragma unroll
            for (int k = 0; k < 11; ++k) hk[k] = hk[k + 1];
            hk[11] = 0xFFFFFFFFu;
        }
        float d = sqrtf(__uint_as_float(m & 0xFFFFF000u));
        int j = (int)(m & 0xFFFu);
        float isdiff = ((int)labs[j] != mylab) ? 1.0f : 0.0f;
        sum_d += d;
        sum_d2 = fmaf(d, d, sum_d2);
        sum_diff += isdiff;
        same_d = fmaf(d, 1.0f - isdiff, same_d);
        if (isdiff > 0.f) bmin = fminf(bmin, d);
    }

    if (q == 0) {
        float nsame = 12.0f - sum_diff;
        float mean_d = sum_d * (1.0f / 12.0f);
        float var = fmaxf(0.f, (sum_d2 - 12.0f * mean_d * mean_d) * (1.0f / 11.0f));
        float md_eps = mean_d + 1e-6f;
        float curvature = sqrtf(var) / md_eps;
        float density = 1.0f / md_eps;
        float same_dist = same_d / (nsame + 1e-6f);
        float bdist = (bmin < 2.9e38f) ? bmin : same_dist;
        float bscore = sum_diff * (1.0f / 12.0f);

        const float* lg = logits + (size_t)(b * NPTS + gi) * 17;
        float v[17];
        float vmax = -3.0e38f;
#pragma unroll
        for (int c = 0; c < 17; ++c) { v[c] = lg[c] * (1.0f / 0.75f); vmax = fmaxf(vmax, v[c]); }
        float ssum = 0.f;
#pragma unroll
        for (int c = 0; c < 17; ++c) { v[c] = expf(v[c] - vmax); ssum += v[c]; }
        float inv = 1.0f / ssum;
        float conf = 0.f, ent = 0.f;
#pragma unroll
        for (int c = 0; c < 17; ++c) {
            float pprob = v[c] * inv;
            conf = fmaxf(conf, pprob);
            ent += pprob * logf(pprob + 1e-8f);
        }
        ent = -ent * (1.0f / 2.8332133f);

        float* op = info32 + (size_t)(b * NPTS + gi) * 32;
        fx4 o0 = {bscore, conf, ent, density};
        fx4 o1v = {curvature, bdist, 0.f, 0.f};
        fx4 zz = {0.f, 0.f, 0.f, 0.f};
        *reinterpret_cast<fx4*>(op + 0)  = o0;
        *reinterpret_cast<fx4*>(op + 4)  = o1v;
        *reinterpret_cast<fx4*>(op + 8)  = zz;
        *reinterpret_cast<fx4*>(op + 12) = zz;
        *reinterpret_cast<fx4*>(op + 16) = zz;
        *reinterpret_cast<fx4*>(op + 20) = zz;
        *reinterpret_cast<fx4*>(op + 24) = zz;
        *reinterpret_cast<fx4*>(op + 28) = zz;
    }
}

// ---------------------------------------------------------------------------
// Generic bf16-MFMA GEMM (boundary-encoder MLP only).
// ---------------------------------------------------------------------------
template<bool AF32, bool RELU, bool NMASK, bool ADDF, bool OUTF, bool OUTB>
__global__ __launch_bounds__(256) void gemm_k(
    const void* __restrict__ Ap, int lda,
    const short* __restrict__ Bt,
    const float* __restrict__ bias,
    float* __restrict__ Cf, int ldcf,
    short* __restrict__ Cb, int ldcb, int cboff,
    const float* __restrict__ Af, int ldaf,
    int N, int K, int ntiles)
{
    __shared__ short As[128 * 40];
    __shared__ short Bs[64 * 40];
    int bid = blockIdx.x;
    int mt = bid / ntiles, nt = bid - mt * ntiles;
    int m0 = mt * 128, n0 = nt * 64;
    int tid = threadIdx.x, l = tid & 63, wid = tid >> 6;
    int wm = wid & 1, wn = wid >> 1, lr = l & 15, lh = l >> 4;
    fx4 acc[4][2] = {};

    int nsteps = K >> 5;
    for (int kt = 0; kt < nsteps; ++kt) {
        int k0 = kt << 5;
        if constexpr (AF32) {
            const float* A = (const float*)Ap;
#pragma unroll
            for (int it = 0; it < 4; ++it) {
                int tt = tid + it * 256;
                int row = tt >> 3, seg = tt & 7;
                fx4 vv = *reinterpret_cast<const fx4*>(A + (size_t)(m0 + row) * lda + k0 + seg * 4);
                s4 w; w[0] = f2b(vv[0]); w[1] = f2b(vv[1]); w[2] = f2b(vv[2]); w[3] = f2b(vv[3]);
                *reinterpret_cast<s4*>(&As[row * 40 + seg * 4]) = w;
            }
        } else {
            const short* A = (const short*)Ap;
#pragma unroll
            for (int it = 0; it < 2; ++it) {
                int tt = tid + it * 256;
                int row = tt >> 2, seg = tt & 3;
                s8 vv = *reinterpret_cast<const s8*>(A + (size_t)(m0 + row) * lda + k0 + seg * 8);
                *reinterpret_cast<s8*>(&As[row * 40 + seg * 8]) = vv;
            }
        }
        {
            int row = tid >> 2, seg = tid & 3;
            s8 vb = {0, 0, 0, 0, 0, 0, 0, 0};
            if (!NMASK || (n0 + row) < N)
                vb = *reinterpret_cast<const s8*>(Bt + (size_t)(n0 + row) * K + k0 + seg * 8);
            *reinterpret_cast<s8*>(&Bs[row * 40 + seg * 8]) = vb;
        }
        __syncthreads();
        s8 af[4], bfr[2];
#pragma unroll
        for (int mf = 0; mf < 4; ++mf)
            af[mf] = *reinterpret_cast<s8*>(&As[(wm * 64 + mf * 16 + lr) * 40 + lh * 8]);
#pragma unroll
        for (int nf = 0; nf < 2; ++nf)
            bfr[nf] = *reinterpret_cast<s8*>(&Bs[(wn * 32 + nf * 16 + lr) * 40 + lh * 8]);
#pragma unroll
        for (int mf = 0; mf < 4; ++mf)
#pragma unroll
            for (int nf = 0; nf < 2; ++nf)
                acc[mf][nf] = __builtin_amdgcn_mfma_f32_16x16x32_bf16(af[mf], bfr[nf], acc[mf][nf], 0, 0, 0);
        __syncthreads();
    }

#pragma unroll
    for (int nf = 0; nf < 2; ++nf) {
        int col = n0 + wn * 32 + nf * 16 + lr;
        if (NMASK && col >= N) continue;
        float bv = bias[col];
#pragma unroll
        for (int mf = 0; mf < 4; ++mf) {
            int r0 = m0 + wm * 64 + mf * 16 + lh * 4;
#pragma unroll
            for (int rg = 0; rg < 4; ++rg) {
                float c = acc[mf][nf][rg] + bv;
                if (RELU) c = fmaxf(c, 0.0f);
                int row = r0 + rg;
                if constexpr (ADDF) c += Af[(size_t)row * ldaf + col];
                if constexpr (OUTF) Cf[(size_t)row * ldcf + col] = c;
                if constexpr (OUTB) Cb[(size_t)row * ldcb + cboff + col] = f2b(c);
            }
        }
    }
}

// ---------------------------------------------------------------------------
// MEGA v10 (R17 best): BM=32, 256 thr, 76.3KB LDS -> 2 blocks/CU; fp
// streamed to thread-private global buffer (no spill, VGPR 112).
// ---------------------------------------------------------------------------
__global__ __launch_bounds__(256, 2) void mega_kernel(
    const short* __restrict__ at0, const short* __restrict__ at1, const short* __restrict__ at2,
    const short* __restrict__ btp0, const short* __restrict__ btp1, const short* __restrict__ btp2,
    const float* __restrict__ bp0, const float* __restrict__ bp1, const float* __restrict__ bp2,
    const short* __restrict__ bta1, const float* __restrict__ ba1,
    const float* __restrict__ Wa2, const float* __restrict__ ba2,
    const short* __restrict__ bto1, const float* __restrict__ bo1,
    const short* __restrict__ bto2, const float* __restrict__ bo2,
    const short* __restrict__ encb, short* __restrict__ fpb,
    float* __restrict__ outf, float* __restrict__ attn_out)
{
    __shared__ alignas(16) short smem[38144];   // 76,288 B
    char* smb = (char*)smem;
    constexpr int BB0 = 0, BB1 = 20480, AB0 = 40960, AB1 = 43008, R2B = 45056, SWF = 75776;
    constexpr size_t FPS = (size_t)512 * 256 * 40;   // shorts per scale
    float* smf = (float*)(smb + SWF);

    int tid = threadIdx.x, l = tid & 63, wid = tid >> 6;
    int lr = l & 15, lh = l >> 4;
    int m0 = blockIdx.x * 32;
    short* fpt = fpb + (size_t)(blockIdx.x * 256 + tid) * 40;

    auto stageB = [&](int bbase, const short* btg, int kt) {
#pragma unroll
        for (int r = 0; r < 5; ++r) {
            int idx = tid + r * 256;
            g2l16(btg + (size_t)kt * 10240 + idx * 8, smb + bbase + idx * 16);
        }
    };
    auto stageA = [&](int abase, const short* atgm, int kt) {
        const short* src = atgm + (size_t)kt * 1024;
        g2l4(src + tid * 2,       smb + abase + tid * 4);
        g2l4(src + 512 + tid * 2, smb + abase + 1024 + tid * 4);
    };
    auto readB = [&](int bbase, s8* bf) {
#pragma unroll
        for (int nf = 0; nf < 5; ++nf) {
            int row = wid * 80 + nf * 16 + lr;
            bf[nf] = *(const s8*)(smb + bbase + row * 64 + ((lh ^ ((row >> 1) & 3)) << 4));
        }
    };
    auto readAp = [&](int abase, s8* af) {
#pragma unroll
        for (int mf = 0; mf < 2; ++mf) {
            int row = mf * 16 + lr;
            af[mf] = *(const s8*)(smb + abase + row * 64 + ((lh ^ ((row >> 1) & 3)) << 4));
        }
    };

    fx4 gacc[2][5] = {};

    auto do_proj = [&](const short* atgm, const short* btg, int ns,
                       const float* bias, short* fpo) {
        fx4 acc[2][5] = {};
        stageB(BB0, btg, 0); stageA(AB0, atgm, 0);
        stageB(BB1, btg, 1); stageA(AB1, atgm, 1);
        LGKM0;
#pragma unroll 1
        for (int kt = 0; kt < ns; ++kt) {
            if (kt < ns - 1) { VMCNT7; } else { VMCNT0; }
            SBAR;
            int cb = (kt & 1) ? BB1 : BB0;
            int ca = (kt & 1) ? AB1 : AB0;
            s8 af[2], bf[5];
            readAp(ca, af);
            readB(cb, bf);
            LGKM0; SCHED0;
            SBAR;
            if (kt + 2 < ns) { stageB(cb, btg, kt + 2); stageA(ca, atgm, kt + 2); }
#pragma unroll
            for (int mf = 0; mf < 2; ++mf)
#pragma unroll
                for (int nf = 0; nf < 5; ++nf)
                    acc[mf][nf] = __builtin_amdgcn_mfma_f32_16x16x32_bf16(af[mf], bf[nf], acc[mf][nf], 0, 0, 0);
        }
        // epilogue: fp -> thread-private global (own elements); gacc accum
#pragma unroll
        for (int nf = 0; nf < 5; ++nf) {
            float bv = bias[wid * 80 + nf * 16 + lr];
#pragma unroll
            for (int mf = 0; mf < 2; ++mf) {
                s4 pk;
#pragma unroll
                for (int rg = 0; rg < 4; ++rg) {
                    float c = acc[mf][nf][rg] + bv;
                    gacc[mf][nf][rg] += c;
                    pk[rg] = f2b(c);
                }
                *(s4*)(fpo + (mf * 5 + nf) * 4) = pk;
            }
        }
    };

    do_proj(at2 + (size_t)blockIdx.x * 24576, btp2, 24, bp2, fpt + 2 * FPS);
    do_proj(at1 + (size_t)blockIdx.x * 16384, btp1, 16, bp1, fpt + 1 * FPS);
    do_proj(at0 + (size_t)blockIdx.x * 8192,  btp0, 8,  bp0, fpt);

    // global mean -> R2 cols 0..319; enc -> cols 320..479 (swizzled writes)
#pragma unroll
    for (int nf = 0; nf < 5; ++nf) {
        int col = wid * 80 + nf * 16 + lr;
#pragma unroll
        for (int mf = 0; mf < 2; ++mf)
#pragma unroll
            for (int rg = 0; rg < 4; ++rg) {
                int row = mf * 16 + lh * 4 + rg;
                int bir = (col * 2) ^ (((row >> 1) & 3) << 4);
                *(short*)(smb + R2B + row * 960 + bir) = f2b(gacc[mf][nf][rg] * (1.0f / 3.0f));
            }
    }
#pragma unroll
    for (int r = 0; r < 3; ++r) {
        int idx = tid + r * 256;
        if (idx < 640) {
            int row = idx / 20, sg = idx - row * 20;
            s8 v = *reinterpret_cast<const s8*>(encb + (size_t)(m0 + row) * 160 + sg * 8);
            int bir = (640 + sg * 16) ^ (((row >> 1) & 3) << 4);
            *(s8*)(smb + R2B + row * 960 + bir) = v;
        }
    }

    auto do_gemm2 = [&](const short* btg, int ns, fx4 (&acc)[2][5]) {
        stageB(BB0, btg, 0);
        stageB(BB1, btg, 1);
        LGKM0;
#pragma unroll 1
        for (int kt = 0; kt < ns; ++kt) {
            if (kt < ns - 1) { VMCNT5; } else { VMCNT0; }
            SBAR;
            int cb = (kt & 1) ? BB1 : BB0;
            s8 af[2], bf[5];
#pragma unroll
            for (int mf = 0; mf < 2; ++mf) {
                int row = mf * 16 + lr;
                int bir = (kt * 64 + (lh << 4)) ^ (((row >> 1) & 3) << 4);
                af[mf] = *(const s8*)(smb + R2B + row * 960 + bir);
            }
            readB(cb, bf);
            LGKM0; SCHED0;
            SBAR;
            if (kt + 2 < ns) stageB(cb, btg, kt + 2);
#pragma unroll
            for (int mf = 0; mf < 2; ++mf)
#pragma unroll
                for (int nf = 0; nf < 5; ++nf)
                    acc[mf][nf] = __builtin_amdgcn_mfma_f32_16x16x32_bf16(af[mf], bf[nf], acc[mf][nf], 0, 0, 0);
        }
    };

    // ---- a1 = relu([global|enc] @ Wa1 + ba1), K=480
    {
        fx4 acc1[2][5] = {};
        do_gemm2(bta1, 15, acc1);
#pragma unroll
        for (int nf = 0; nf < 5; ++nf) {
            int col = wid * 80 + nf * 16 + lr;
            float bv = ba1[col];
#pragma unroll
            for (int mf = 0; mf < 2; ++mf)
#pragma unroll
                for (int rg = 0; rg < 4; ++rg) {
                    int row = mf * 16 + lh * 4 + rg;
                    int bir = (col * 2) ^ (((row >> 1) & 3) << 4);
                    *(short*)(smb + R2B + row * 960 + bir) = f2b(fmaxf(acc1[mf][nf][rg] + bv, 0.0f));
                }
        }
    }

    // ---- a2 via VALU: 8 lanes/row; Wa2 f32 staged in BB0 region
    {
        float* ws2 = (float*)smb;
        if (tid < 240)
            reinterpret_cast<fx4*>(ws2)[tid] = reinterpret_cast<const fx4*>(Wa2)[tid];
        __syncthreads();
        int row = tid >> 3, g = tid & 7;
        float l0 = 0.f, l1 = 0.f, l2 = 0.f;
#pragma unroll
        for (int j = 0; j < 5; ++j) {
            int bir = (g * 80 + j * 16) ^ (((row >> 1) & 3) << 4);
            s8 v = *(const s8*)(smb + R2B + row * 960 + bir);
#pragma unroll
            for (int u = 0; u < 8; ++u) {
                float f = b2f(v[u]);
                const float* wp = ws2 + (g * 40 + j * 8 + u) * 3;
                l0 = fmaf(f, wp[0], l0);
                l1 = fmaf(f, wp[1], l1);
                l2 = fmaf(f, wp[2], l2);
            }
        }
#pragma unroll
        for (int s = 4; s >= 1; s >>= 1) {
            l0 += __shfl_xor(l0, s, 8);
            l1 += __shfl_xor(l1, s, 8);
            l2 += __shfl_xor(l2, s, 8);
        }
        if (g == 0) {
            l0 += ba2[0]; l1 += ba2[1]; l2 += ba2[2];
            float mx = fmaxf(l0, fmaxf(l1, l2));
            float e0 = expf(l0 - mx), e1 = expf(l1 - mx), e2 = expf(l2 - mx);
            float inv = 1.0f / (e0 + e1 + e2);
            float w0 = e0 * inv, w1 = e1 * inv, w2 = e2 * inv;
            attn_out[(size_t)(m0 + row) * 3 + 0] = w0;
            attn_out[(size_t)(m0 + row) * 3 + 1] = w1;
            attn_out[(size_t)(m0 + row) * 3 + 2] = w2;
            smf[row * 4 + 0] = w0; smf[row * 4 + 1] = w1; smf[row * 4 + 2] = w2;
        }
        __syncthreads();
    }

    // ---- fused = sum_s w_s * fp_s (read back own global fp) -> R2
#pragma unroll
    for (int mf = 0; mf < 2; ++mf)
#pragma unroll
        for (int nf = 0; nf < 5; ++nf) {
            s4 p0 = *(const s4*)(fpt + (mf * 5 + nf) * 4);
            s4 p1 = *(const s4*)(fpt + 1 * FPS + (mf * 5 + nf) * 4);
            s4 p2 = *(const s4*)(fpt + 2 * FPS + (mf * 5 + nf) * 4);
            int col = wid * 80 + nf * 16 + lr;
#pragma unroll
            for (int rg = 0; rg < 4; ++rg) {
                int row = mf * 16 + lh * 4 + rg;
                float fv = smf[row * 4 + 0] * b2f(p0[rg])
                         + smf[row * 4 + 1] * b2f(p1[rg])
                         + smf[row * 4 + 2] * b2f(p2[rg]);
                int bir = (col * 2) ^ (((row >> 1) & 3) << 4);
                *(short*)(smb + R2B + row * 960 + bir) = f2b(fv);
            }
        }

    // ---- h = relu(fused @ Wo1 + bo1)
    {
        fx4 acch[2][5] = {};
        do_gemm2(bto1, 10, acch);
#pragma unroll
        for (int nf = 0; nf < 5; ++nf) {
            int col = wid * 80 + nf * 16 + lr;
            float bv = bo1[col];
#pragma unroll
            for (int mf = 0; mf < 2; ++mf)
#pragma unroll
                for (int rg = 0; rg < 4; ++rg) {
                    int row = mf * 16 + lh * 4 + rg;
                    int bir = (col * 2) ^ (((row >> 1) & 3) << 4);
                    *(short*)(smb + R2B + row * 960 + bir) = f2b(fmaxf(acch[mf][nf][rg] + bv, 0.0f));
                }
        }
    }

    // ---- out = h @ Wo2 + bo2 + gacc/3 (residual in regs)
    {
        fx4 acco[2][5] = {};
        do_gemm2(bto2, 10, acco);
#pragma unroll
        for (int nf = 0; nf < 5; ++nf) {
            int col = wid * 80 + nf * 16 + lr;
            float bv = bo2[col];
#pragma unroll
            for (int mf = 0; mf < 2; ++mf)
#pragma unroll
                for (int rg = 0; rg < 4; ++rg) {
                    int row = m0 + mf * 16 + lh * 4 + rg;
                    float c = acco[mf][nf][rg] + bv + gacc[mf][nf][rg] * (1.0f / 3.0f);
                    outf[(size_t)row * 320 + col] = c;
                }
        }
    }
}

// ---------------------------------------------------------------------------
extern "C" void kernel_launch(void* const* d_in, const int* in_sizes, int n_in,
                              void* d_out, int out_size, void* d_ws, size_t ws_size,
                              hipStream_t stream)
{
    const float* feat0  = (const float*)d_in[0];
    const float* feat1  = (const float*)d_in[1];
    const float* feat2  = (const float*)d_in[2];
    const float* logits = (const float*)d_in[3];
    const int*   labels = (const int*)d_in[4];
    const float* pos    = (const float*)d_in[5];
    const float* Wp0 = (const float*)d_in[6];   const float* bp0 = (const float*)d_in[7];
    const float* Wp1 = (const float*)d_in[8];   const float* bp1 = (const float*)d_in[9];
    const float* Wp2 = (const float*)d_in[10];  const float* bp2 = (const float*)d_in[11];
    const float* Wbe1 = (const float*)d_in[12]; const float* bbe1 = (const float*)d_in[13];
    const float* Wbe2 = (const float*)d_in[14]; const float* bbe2 = (const float*)d_in[15];
    const float* Wa1 = (const float*)d_in[16];  const float* ba1 = (const float*)d_in[17];
    const float* Wa2 = (const float*)d_in[18];  const float* ba2 = (const float*)d_in[19];
    const float* Wo1 = (const float*)d_in[20];  const float* bo1 = (const float*)d_in[21];
    const float* Wo2 = (const float*)d_in[22];  const float* bo2 = (const float*)d_in[23];

    char* p = (char*)d_ws;
    auto alloc = [&](size_t bytes) { char* r = p; p += (bytes + 255) & ~(size_t)255; return r; };
    short* bt_p0  = (short*)alloc((size_t)320 * 256 * 2);
    short* bt_p1  = (short*)alloc((size_t)320 * 512 * 2);
    short* bt_p2  = (short*)alloc((size_t)320 * 768 * 2);
    short* bt_be1 = (short*)alloc((size_t)96 * 32 * 2);
    short* bt_be2 = (short*)alloc((size_t)160 * 96 * 2);
    short* bt_a1  = (short*)alloc((size_t)320 * 480 * 2);
    short* bt_o1  = (short*)alloc((size_t)320 * 320 * 2);
    short* bt_o2  = (short*)alloc((size_t)320 * 320 * 2);
    float* info32 = (float*)alloc((size_t)MTOT * 32 * 4);
    short* h1     = (short*)alloc((size_t)MTOT * 96 * 2);
    short* encb   = (short*)alloc((size_t)MTOT * 160 * 2);
    u32*   knnkeys= (u32*)alloc((size_t)MTOT * 4 * 12 * 4);
    short* abt0   = (short*)alloc((size_t)MTOT * 256 * 2);
    short* abt1   = (short*)alloc((size_t)MTOT * 512 * 2);
    short* abt2   = (short*)alloc((size_t)MTOT * 768 * 2);
    short* fpb    = (short*)alloc((size_t)3 * 512 * 256 * 40 * 2);   // 31.5 MB

    float* outf = (float*)d_out;
    float* attn_out = outf + (size_t)MTOT * 320;

    WTDesc wd;
    const float* Ws[8] = {Wp0, Wp1, Wp2, Wbe1, Wbe2, Wa1, Wo1, Wo2};
    short* Bts[8] = {bt_p0, bt_p1, bt_p2, bt_be1, bt_be2, bt_a1, bt_o1, bt_o2};
    int Ks[8]  = {256, 512, 768, 6, 96, 480, 320, 320};
    int Ns[8]  = {320, 320, 320, 96, 160, 320, 320, 320};
    int Kps[8] = {256, 512, 768, 32, 96, 480, 320, 320};
    int Sz[8]  = {1, 1, 1, 0, 0, 1, 1, 1};
    int acc = 0;
    for (int s = 0; s < 8; ++s) {
        wd.W[s] = Ws[s]; wd.Bt[s] = Bts[s];
        wd.K[s] = Ks[s]; wd.N[s] = Ns[s]; wd.Kp[s] = Kps[s]; wd.swz[s] = Sz[s];
        wd.base[s] = acc;
        acc += Ns[s] * Kps[s];
    }
    wd.base[8] = acc;
    wtrans8_kernel<<<(acc + 255) / 256, 256, 0, stream>>>(wd);

    // segregated: blocks 0..1023 knn (fill CUs with VALU work first),
    // 1024..7167 aprep (BW-bound backfill; template-const indexing)
    knap_kernel<<<7168, 512, 0, stream>>>(pos, knnkeys,
                                          feat0, feat1, feat2,
                                          abt0, abt1, abt2);
    knn_merge_kernel<<<256, 256, 0, stream>>>(knnkeys, labels, logits, info32);

    // info -> h1 (relu), N=96, K=32
    gemm_k<true, true, true, false, false, true><<<256, 256, 0, stream>>>(
        info32, 32, bt_be1, bbe1, nullptr, 0, h1, 96, 0, nullptr, 0, 96, 32, 2);
    // h1 -> enc (relu), N=160, K=96
    gemm_k<false, true, true, false, false, true><<<384, 256, 0, stream>>>(
        h1, 96, bt_be2, bbe2, nullptr, 0, encb, 160, 0, nullptr, 0, 160, 96, 3);

    mega_kernel<<<512, 256, 0, stream>>>(
        abt0, abt1, abt2,
        bt_p0, bt_p1, bt_p2,
        bp0, bp1, bp2,
        bt_a1, ba1, Wa2, ba2,
        bt_o1, bo1, bt_o2, bo2,
        encb, fpb, outf, attn_out);
}